// Round 3
// baseline (834.294 us; speedup 1.0000x reference)
//
#include <hip/hip_runtime.h>
#include <hip/hip_bf16.h>
#include <cstdint>
#include <cstddef>

#define KD 512
#define KP 1536  // packed K = 3*512

// ---- workspace byte offsets ----
#define OFF_CN   0u           // 4096 f32 coarse codebook norms
#define OFF_FN   16384u       // 8192 f32 fine codebook norms
#define OFF_ZN   49152u       // 8192 f32 z-coarse row norms
#define OFF_RN   81920u       // 8192 f32 residual row norms
#define OFF_LOSS 114688u      // 1 f32 loss accumulator
#define OFF_AMC  114944u      // 8192 u64 coarse argmin keys
#define OFF_AMF  180480u      // 8192 u64 fine argmin keys
#define OFF_CE1  246016u      // 4096x1536 bf16 coarse emb pack-B [hi|lo|hi]
#define OFF_FE1  12828928u    // 8192x1536 bf16 fine emb pack-B [hi|lo|hi]
#define OFF_W1   37994752u    // 512x1536 bf16 w_c2f pack-A [hi|hi|lo]
#define OFF_W2   39567616u    // 512x1536 bf16 w_f2c pack-A [hi|hi|lo]
#define OFF_SH   41140480u    // shared 25.17MB: zc_pack (dead after coarse VQ)
                              //   then h (fp32, 16.78MB) + infl (bf16, 8.39MB)
#define OFF_H    41140480u
#define OFF_INFL 57917696u
#define OFF_R2   66306304u    // 8192x1536 bf16 residual pack-A [hi|hi|lo]
// total = 91,472,128 bytes (< round-2's proven 92.5MB)

typedef __attribute__((ext_vector_type(8))) short bf16x8;
typedef __attribute__((ext_vector_type(4))) float f32x4;

__device__ __forceinline__ float block_sum(float v, float* sred) {
#pragma unroll
  for (int off = 32; off > 0; off >>= 1) v += __shfl_down(v, off, 64);
  if ((threadIdx.x & 63) == 0) sred[threadIdx.x >> 6] = v;
  __syncthreads();
  float r = sred[0] + sred[1] + sred[2] + sred[3];
  __syncthreads();
  return r;
}

__device__ __forceinline__ float sigmoidf_(float x) { return 1.0f / (1.0f + expf(-x)); }

__device__ __forceinline__ void split_bf16(float v, __hip_bfloat16* hi, __hip_bfloat16* lo) {
  __hip_bfloat16 h = __float2bfloat16(v);
  *hi = h;
  *lo = __float2bfloat16(v - __bfloat162float(h));
}

// ---- prep: norms + packed hi/lo rows ----
// blocks: [0,4096) ce->pack-B, [4096,12288) fe->pack-B, [12288,20480) z-coarse->pack-A,
//         [20480,20992) w_c2f->pack-A, [20992,21504) w_f2c->pack-A
__global__ __launch_bounds__(256) void prep(
    const float* __restrict__ ce, const float* __restrict__ fe, const float* __restrict__ z,
    const float* __restrict__ w1, const float* __restrict__ w2,
    float* __restrict__ cn, float* __restrict__ fn, float* __restrict__ zn,
    __hip_bfloat16* __restrict__ ce1, __hip_bfloat16* __restrict__ fe1,
    __hip_bfloat16* __restrict__ zc2, __hip_bfloat16* __restrict__ w1p,
    __hip_bfloat16* __restrict__ w2p, float* __restrict__ lossp) {
  __shared__ float sred[4];
  const int b = blockIdx.x, t = threadIdx.x;
  const float* src;
  float* nd = nullptr;
  __hip_bfloat16* dst;
  int packB;  // 1: [hi|lo|hi] (codebooks), 0: [hi|hi|lo] (queries/weights)
  size_t row;
  if (b < 4096) {
    src = ce + (size_t)b * KD; nd = cn + b; dst = ce1; row = b; packB = 1;
  } else if (b < 12288) {
    row = b - 4096; src = fe + row * KD; nd = fn + row; dst = fe1; packB = 1;
  } else if (b < 20480) {
    row = b - 12288; src = z + row * 1024; nd = zn + row; dst = zc2; packB = 0;
  } else if (b < 20992) {
    row = b - 20480; src = w1 + row * KD; dst = w1p; packB = 0;
  } else {
    row = b - 20992; src = w2 + row * KD; dst = w2p; packB = 0;
  }
  float acc = 0.0f;
  __hip_bfloat16* base = dst + row * KP;
#pragma unroll
  for (int j = 0; j < 2; ++j) {
    int c = t + j * 256;
    float v = src[c];
    acc += v * v;
    __hip_bfloat16 h, l;
    split_bf16(v, &h, &l);
    if (packB) {  // [hi | lo | hi]
      base[c] = h; base[KD + c] = l; base[2 * KD + c] = h;
    } else {      // [hi | hi | lo]
      base[c] = h; base[KD + c] = h; base[2 * KD + c] = l;
    }
  }
  if (nd) {
    float s = block_sum(acc, sred);
    if (t == 0) nd[0] = s;
  }
  if (b == 20480 && t == 0) lossp[0] = 0.0f;
}

// ---- m97-style bf16 GEMM, K=1536, 128x128 tile, fused epilogues ----
// eMode 0: argmin (d = rowNorm+colNorm-2*acc -> atomicMin u64 key)
// eMode 1: store C[row*512+col] = acc + bias[col]
// gather != null: A rows gathered via low 32 bits of gather[row]
__global__ __launch_bounds__(256) void gemm_p(
    const __hip_bfloat16* __restrict__ A, const unsigned long long* __restrict__ gather,
    const __hip_bfloat16* __restrict__ B,
    const float* __restrict__ rowNorm, const float* __restrict__ colNorm,
    unsigned long long* __restrict__ amin,
    const float* __restrict__ bias, float* __restrict__ C, int eMode) {
  __shared__ __align__(16) __hip_bfloat16 sA[128 * 32];
  __shared__ __align__(16) __hip_bfloat16 sB[128 * 32];
  const int t = threadIdx.x;
  const int w = t >> 6, l = t & 63;
  const int rowTile = blockIdx.y << 7;
  const int colTile = blockIdx.x << 7;
  const int wr = (w >> 1) << 6;
  const int wc = (w & 1) << 6;

  const int srow = t >> 2;      // 0..63 (staged row within half-tile)
  const int sk = (t & 3) << 3;  // k element offset 0/8/16/24

  size_t aRow0, aRow1;
  if (gather) {
    aRow0 = (size_t)(unsigned)(gather[rowTile + srow] & 0xffffffffULL) * KP;
    aRow1 = (size_t)(unsigned)(gather[rowTile + 64 + srow] & 0xffffffffULL) * KP;
  } else {
    aRow0 = (size_t)(rowTile + srow) * KP;
    aRow1 = (size_t)(rowTile + 64 + srow) * KP;
  }
  const size_t bRow0 = (size_t)(colTile + srow) * KP;
  const size_t bRow1 = (size_t)(colTile + 64 + srow) * KP;

  f32x4 acc[4][4];
#pragma unroll
  for (int i = 0; i < 4; ++i)
#pragma unroll
    for (int j = 0; j < 4; ++j) acc[i][j] = (f32x4){0.f, 0.f, 0.f, 0.f};

  const int fr = l & 15;
  const int kq = (l >> 4) << 3;
  const int ldsW = (w << 4) << 5;  // wave's staging dest base (w*16 rows * 32)

  for (int kk = 0; kk < KP; kk += 32) {
    __syncthreads();  // previous chunk's ds_reads done before overwrite
    __builtin_amdgcn_global_load_lds(
        (const __attribute__((address_space(1))) unsigned*)(A + aRow0 + kk + sk),
        (__attribute__((address_space(3))) unsigned*)(sA + ldsW), 16, 0, 0);
    __builtin_amdgcn_global_load_lds(
        (const __attribute__((address_space(1))) unsigned*)(A + aRow1 + kk + sk),
        (__attribute__((address_space(3))) unsigned*)(sA + 2048 + ldsW), 16, 0, 0);
    __builtin_amdgcn_global_load_lds(
        (const __attribute__((address_space(1))) unsigned*)(B + bRow0 + kk + sk),
        (__attribute__((address_space(3))) unsigned*)(sB + ldsW), 16, 0, 0);
    __builtin_amdgcn_global_load_lds(
        (const __attribute__((address_space(1))) unsigned*)(B + bRow1 + kk + sk),
        (__attribute__((address_space(3))) unsigned*)(sB + 2048 + ldsW), 16, 0, 0);
    __syncthreads();  // staging complete

    bf16x8 af[4], bf[4];
#pragma unroll
    for (int mt = 0; mt < 4; ++mt)
      af[mt] = *(const bf16x8*)(sA + ((wr + (mt << 4) + fr) << 5) + kq);
#pragma unroll
    for (int nt = 0; nt < 4; ++nt)
      bf[nt] = *(const bf16x8*)(sB + ((wc + (nt << 4) + fr) << 5) + kq);
#pragma unroll
    for (int mt = 0; mt < 4; ++mt)
#pragma unroll
      for (int nt = 0; nt < 4; ++nt)
        acc[mt][nt] = __builtin_amdgcn_mfma_f32_16x16x32_bf16(af[mt], bf[nt], acc[mt][nt], 0, 0, 0);
  }

  const int quad = l >> 4;
  if (eMode == 0) {
    // C/D layout: col = lane&15, row = quad*4 + reg
#pragma unroll
    for (int mt = 0; mt < 4; ++mt) {
#pragma unroll
      for (int reg = 0; reg < 4; ++reg) {
        const int row = rowTile + wr + (mt << 4) + (quad << 2) + reg;
        const float xn = rowNorm[row];
        unsigned long long key = ~0ULL;
#pragma unroll
        for (int nt = 0; nt < 4; ++nt) {
          const int col = colTile + wc + (nt << 4) + fr;
          float d = (xn + colNorm[col]) - 2.0f * acc[mt][nt][reg];
          unsigned ub = __float_as_uint(d);
          ub = (ub & 0x80000000u) ? ~ub : (ub | 0x80000000u);
          unsigned long long k2 = ((unsigned long long)ub << 32) | (unsigned long long)(unsigned)col;
          if (k2 < key) key = k2;
        }
#pragma unroll
        for (int off = 1; off < 16; off <<= 1) {
          unsigned long long o = __shfl_xor(key, off, 64);
          if (o < key) key = o;
        }
        if (fr == 0) atomicMin(amin + row, key);
      }
    }
  } else {
#pragma unroll
    for (int mt = 0; mt < 4; ++mt) {
#pragma unroll
      for (int reg = 0; reg < 4; ++reg) {
        const int row = rowTile + wr + (mt << 4) + (quad << 2) + reg;
#pragma unroll
        for (int nt = 0; nt < 4; ++nt) {
          const int col = colTile + wc + (nt << 4) + fr;
          C[(size_t)row * KD + col] = acc[mt][nt][reg] + bias[col];
        }
      }
    }
  }
}

// ---- LN + leaky -> influence(bf16); residual pack-A + norms ----
__global__ __launch_bounds__(256) void ln_residual(
    const float* __restrict__ h, const float* __restrict__ g, const float* __restrict__ be,
    const float* __restrict__ z, const float* __restrict__ gRaw,
    __hip_bfloat16* __restrict__ infl, float* __restrict__ rn,
    __hip_bfloat16* __restrict__ r2) {
  __shared__ float sred[4];
  const int row = blockIdx.x, t = threadIdx.x;
  const size_t base = (size_t)row * KD;
  float h0 = h[base + t], h1 = h[base + t + 256];
  float m = block_sum(h0 + h1, sred) * (1.0f / 512.0f);
  float d0 = h0 - m, d1 = h1 - m;
  float var = block_sum(d0 * d0 + d1 * d1, sred) * (1.0f / 512.0f);
  float sq = sqrtf(var + 1e-5f);
  float gc = sigmoidf_(gRaw[0]);
  float v0 = d0 / sq * g[t] + be[t];
  float v1 = d1 / sq * g[t + 256] + be[t + 256];
  v0 = v0 > 0.0f ? v0 : 0.1f * v0;
  v1 = v1 > 0.0f ? v1 : 0.1f * v1;
  infl[base + t] = __float2bfloat16(v0);
  infl[base + t + 256] = __float2bfloat16(v1);
  float zf0 = z[(size_t)row * 1024 + 512 + t];
  float zf1 = z[(size_t)row * 1024 + 512 + t + 256];
  float r0 = zf0 - gc * v0, r1 = zf1 - gc * v1;
  __hip_bfloat16* rb = r2 + (size_t)row * KP;
  __hip_bfloat16 hh, ll;
  split_bf16(r0, &hh, &ll);
  rb[t] = hh; rb[KD + t] = hh; rb[2 * KD + t] = ll;  // pack-A [hi|hi|lo]
  split_bf16(r1, &hh, &ll);
  rb[t + 256] = hh; rb[KD + t + 256] = hh; rb[2 * KD + t + 256] = ll;
  float rs = block_sum(r0 * r0 + r1 * r1, sred);
  if (t == 0) rn[row] = rs;
}

// ---- LN+leaky on h2, gather q_c/q_f, outputs + loss partials ----
__global__ __launch_bounds__(256) void finalize(
    const float* __restrict__ h, const float* __restrict__ g, const float* __restrict__ be,
    const __hip_bfloat16* __restrict__ infl,
    const unsigned long long* __restrict__ amc, const unsigned long long* __restrict__ amf,
    const float* __restrict__ z, const float* __restrict__ ce, const float* __restrict__ fe,
    const float* __restrict__ gcRaw, const float* __restrict__ gfRaw,
    float* __restrict__ out, float* __restrict__ lossp) {
  __shared__ float sred[4];
  const int row = blockIdx.x, t = threadIdx.x;
  const size_t base = (size_t)row * KD;
  float h0 = h[base + t], h1 = h[base + t + 256];
  float m = block_sum(h0 + h1, sred) * (1.0f / 512.0f);
  float d0 = h0 - m, d1 = h1 - m;
  float var = block_sum(d0 * d0 + d1 * d1, sred) * (1.0f / 512.0f);
  float sq = sqrtf(var + 1e-5f);
  float fb0 = d0 / sq * g[t] + be[t];
  float fb1 = d1 / sq * g[t + 256] + be[t + 256];
  fb0 = fb0 > 0.0f ? fb0 : 0.1f * fb0;
  fb1 = fb1 > 0.0f ? fb1 : 0.1f * fb1;
  float gc = sigmoidf_(gcRaw[0]);
  float gf = sigmoidf_(gfRaw[0]);
  unsigned ic = (unsigned)(amc[row] & 0xffffffffULL);
  unsigned ifx = (unsigned)(amf[row] & 0xffffffffULL);
  float loc = 0.0f;
#pragma unroll
  for (int j = 0; j < 2; ++j) {
    int c = t + j * 256;
    float fb = j ? fb1 : fb0;
    float qc = ce[(size_t)ic * KD + c];
    float qf = fe[(size_t)ifx * KD + c];
    float zc = z[(size_t)row * 1024 + c];
    float zf = z[(size_t)row * 1024 + 512 + c];
    float fl = __bfloat162float(infl[base + c]);
    out[(size_t)row * 1024 + c] = qc + 0.1f * gf * fb;
    out[(size_t)row * 1024 + 512 + c] = qf + gc * fl;
    float dc = qc - zc;
    float res = zf - gc * fl;
    float df = qf - res;
    loc += dc * dc + df * df;
  }
  float ls = block_sum(loc, sred);
  if (t == 0) atomicAdd(lossp, ls);
}

__global__ void loss_write(const float* __restrict__ lossp, float* __restrict__ out) {
  out[0] = 1.25f * lossp[0] / (8192.0f * 512.0f);
}

extern "C" void kernel_launch(void* const* d_in, const int* in_sizes, int n_in,
                              void* d_out, int out_size, void* d_ws, size_t ws_size,
                              hipStream_t stream) {
  const float* z      = (const float*)d_in[0];
  const float* ce     = (const float*)d_in[1];
  const float* fe     = (const float*)d_in[2];
  const float* w_c2f  = (const float*)d_in[3];
  const float* b_c2f  = (const float*)d_in[4];
  const float* g_c2f  = (const float*)d_in[5];
  const float* be_c2f = (const float*)d_in[6];
  const float* w_f2c  = (const float*)d_in[7];
  const float* b_f2c  = (const float*)d_in[8];
  const float* g_f2c  = (const float*)d_in[9];
  const float* be_f2c = (const float*)d_in[10];
  const float* gcRaw  = (const float*)d_in[11];
  const float* gfRaw  = (const float*)d_in[12];
  float* out = (float*)d_out;
  char* ws = (char*)d_ws;

  float* cn = (float*)(ws + OFF_CN);
  float* fn = (float*)(ws + OFF_FN);
  float* zn = (float*)(ws + OFF_ZN);
  float* rn = (float*)(ws + OFF_RN);
  float* lossp = (float*)(ws + OFF_LOSS);
  unsigned long long* amc = (unsigned long long*)(ws + OFF_AMC);
  unsigned long long* amf = (unsigned long long*)(ws + OFF_AMF);
  __hip_bfloat16* ce1 = (__hip_bfloat16*)(ws + OFF_CE1);
  __hip_bfloat16* fe1 = (__hip_bfloat16*)(ws + OFF_FE1);
  __hip_bfloat16* w1p = (__hip_bfloat16*)(ws + OFF_W1);
  __hip_bfloat16* w2p = (__hip_bfloat16*)(ws + OFF_W2);
  __hip_bfloat16* zc2 = (__hip_bfloat16*)(ws + OFF_SH);
  float* h = (float*)(ws + OFF_H);
  __hip_bfloat16* infl = (__hip_bfloat16*)(ws + OFF_INFL);
  __hip_bfloat16* r2 = (__hip_bfloat16*)(ws + OFF_R2);

  // init argmin keys (coarse+fine contiguous) to u64 max
  hipMemsetAsync(ws + OFF_AMC, 0xFF, 131072, stream);

  // norms + packed hi/lo rows; zero loss
  prep<<<21504, 256, 0, stream>>>(ce, fe, z, w_c2f, w_f2c, cn, fn, zn,
                                  ce1, fe1, zc2, w1p, w2p, lossp);

  // coarse VQ: 8192 x 4096, K=1536 packed, argmin
  gemm_p<<<dim3(32, 64), 256, 0, stream>>>(zc2, nullptr, ce1, zn, cn, amc,
                                           nullptr, nullptr, 0);

  // MLP1: h = gather(ce1, amc) @ w1p^T + b  (pack-B x pack-A = 3 terms)
  gemm_p<<<dim3(4, 64), 256, 0, stream>>>(ce1, amc, w1p, nullptr, nullptr, nullptr,
                                          b_c2f, h, 1);

  // LN + leaky -> influence (bf16); residual pack-A + norms
  ln_residual<<<8192, 256, 0, stream>>>(h, g_c2f, be_c2f, z, gcRaw, infl, rn, r2);

  // fine VQ: 8192 x 8192, K=1536 packed, argmin
  gemm_p<<<dim3(64, 64), 256, 0, stream>>>(r2, nullptr, fe1, rn, fn, amf,
                                           nullptr, nullptr, 0);

  // MLP2: h = gather(fe1, amf) @ w2p^T + b
  gemm_p<<<dim3(4, 64), 256, 0, stream>>>(fe1, amf, w2p, nullptr, nullptr, nullptr,
                                          b_f2c, h, 1);

  // outputs + loss
  finalize<<<8192, 256, 0, stream>>>(h, g_f2c, be_f2c, infl, amc, amf, z, ce, fe,
                                     gcRaw, gfRaw, out, lossp);
  loss_write<<<1, 1, 0, stream>>>(lossp, out + (size_t)8192 * 1024);
}

// Round 4
// 697.562 us; speedup vs baseline: 1.1960x; 1.1960x over previous
//
#include <hip/hip_runtime.h>
#include <hip/hip_bf16.h>
#include <cstdint>
#include <cstddef>

#define KD 512
#define BK 32

// ---- workspace byte offsets ----
#define OFF_CN   0u           // 4096 f32 coarse codebook norms
#define OFF_FN   16384u       // 8192 f32 fine codebook norms
#define OFF_ZN   49152u       // 8192 f32 z-coarse row norms
#define OFF_RN   81920u       // 8192 f32 residual row norms
#define OFF_LOSS 114688u      // 1 f32 loss accumulator
#define OFF_AMC  114944u      // 8192 u64 coarse argmin keys
#define OFF_AMF  180480u      // 8192 u64 fine argmin keys
#define OFF_CEH  246016u      // 4096x512 bf16
#define OFF_CEL  4440320u
#define OFF_FEH  8634624u     // 8192x512 bf16
#define OFF_FEL  17023232u
#define OFF_ZCH  25411840u    // 8192x512 bf16
#define OFF_ZCL  33800448u
#define OFF_RH   42189056u    // 8192x512 bf16 residual
#define OFF_RL   50577664u
#define OFF_W1H  58966272u    // 512x512 bf16
#define OFF_W1L  59490560u
#define OFF_W2H  60014848u
#define OFF_W2L  60539136u
#define OFF_H    61063424u    // 8192x512 f32
#define OFF_INFL 77840640u    // 8192x512 bf16
// total = 86,229,248 bytes (< round-2's proven 92.5MB)

typedef __attribute__((ext_vector_type(8))) short bf16x8;
typedef __attribute__((ext_vector_type(4))) float f32x4;

__device__ __forceinline__ float block_sum(float v, float* sred) {
#pragma unroll
  for (int off = 32; off > 0; off >>= 1) v += __shfl_down(v, off, 64);
  if ((threadIdx.x & 63) == 0) sred[threadIdx.x >> 6] = v;
  __syncthreads();
  float r = sred[0] + sred[1] + sred[2] + sred[3];
  __syncthreads();
  return r;
}

__device__ __forceinline__ float sigmoidf_(float x) { return 1.0f / (1.0f + expf(-x)); }

__device__ __forceinline__ void split_bf16(float v, __hip_bfloat16* hi, __hip_bfloat16* lo) {
  __hip_bfloat16 h = __float2bfloat16(v);
  *hi = h;
  *lo = __float2bfloat16(v - __bfloat162float(h));
}

// ---- prep: norms + hi/lo split for ce / fe / z-coarse / w1 / w2 ----
__global__ __launch_bounds__(256) void prep(
    const float* __restrict__ ce, const float* __restrict__ fe, const float* __restrict__ z,
    const float* __restrict__ w1, const float* __restrict__ w2,
    float* __restrict__ cn, float* __restrict__ fn, float* __restrict__ zn,
    __hip_bfloat16* __restrict__ ceH, __hip_bfloat16* __restrict__ ceL,
    __hip_bfloat16* __restrict__ feH, __hip_bfloat16* __restrict__ feL,
    __hip_bfloat16* __restrict__ zcH, __hip_bfloat16* __restrict__ zcL,
    __hip_bfloat16* __restrict__ w1H, __hip_bfloat16* __restrict__ w1L,
    __hip_bfloat16* __restrict__ w2H, __hip_bfloat16* __restrict__ w2L,
    float* __restrict__ lossp) {
  __shared__ float sred[4];
  const int b = blockIdx.x, t = threadIdx.x;
  const float* src;
  float* nd = nullptr;
  __hip_bfloat16 *dh, *dl;
  size_t row;
  if (b < 4096) {
    row = b; src = ce + row * KD; nd = cn + row; dh = ceH; dl = ceL;
  } else if (b < 12288) {
    row = b - 4096; src = fe + row * KD; nd = fn + row; dh = feH; dl = feL;
  } else if (b < 20480) {
    row = b - 12288; src = z + row * 1024; nd = zn + row; dh = zcH; dl = zcL;
  } else if (b < 20992) {
    row = b - 20480; src = w1 + row * KD; dh = w1H; dl = w1L;
  } else {
    row = b - 20992; src = w2 + row * KD; dh = w2H; dl = w2L;
  }
  float acc = 0.0f;
#pragma unroll
  for (int j = 0; j < 2; ++j) {
    int c = t + j * 256;
    float v = src[c];
    acc += v * v;
    __hip_bfloat16 h, l;
    split_bf16(v, &h, &l);
    dh[row * KD + c] = h;
    dl[row * KD + c] = l;
  }
  if (nd) {
    float s = block_sum(acc, sred);
    if (t == 0) nd[0] = s;
  }
  if (b == 20480 && t == 0) lossp[0] = 0.0f;
}

// ---- bf16x3 MFMA GEMM, 128x128 tile, swizzled LDS, reg-staged pipeline ----
// dot = Ah*Bh + Ah*Bl + Al*Bh (fp32 accum). eMode 0: argmin; 1: store+bias.
__global__ __launch_bounds__(256) void gemm4(
    const __hip_bfloat16* __restrict__ Ah, const __hip_bfloat16* __restrict__ Al,
    const unsigned long long* __restrict__ gather,
    const __hip_bfloat16* __restrict__ Bh, const __hip_bfloat16* __restrict__ Bl,
    const float* __restrict__ rowNorm, const float* __restrict__ colNorm,
    unsigned long long* __restrict__ amin,
    const float* __restrict__ bias, float* __restrict__ C, int eMode) {
  __shared__ __align__(16) __hip_bfloat16 sAh[128 * 32];
  __shared__ __align__(16) __hip_bfloat16 sAl[128 * 32];
  __shared__ __align__(16) __hip_bfloat16 sBh[128 * 32];
  __shared__ __align__(16) __hip_bfloat16 sBl[128 * 32];
  const int t = threadIdx.x;
  const int w = t >> 6, l = t & 63;
  const int rowTile = blockIdx.y << 7;
  const int colTile = blockIdx.x << 7;
  const int wr = (w >> 1) << 6;
  const int wc = (w & 1) << 6;

  // staging: thread t covers rows srow, srow+64; 16B k-block sb of each array
  const int srow = t >> 2;
  const int sb = t & 3;
  const int skE = sb << 3;  // k elem offset in global row
  const int swz = (sb ^ ((srow >> 1) & 3)) << 3;  // swizzled block position
  const int wOff0 = (srow << 5) + swz;
  const int wOff1 = ((srow + 64) << 5) + swz;  // ((srow+64)>>1)&3 == (srow>>1)&3

  size_t ar0, ar1;
  if (gather) {
    ar0 = (size_t)(unsigned)(gather[rowTile + srow] & 0xffffffffULL) * KD;
    ar1 = (size_t)(unsigned)(gather[rowTile + 64 + srow] & 0xffffffffULL) * KD;
  } else {
    ar0 = (size_t)(rowTile + srow) * KD;
    ar1 = (size_t)(rowTile + 64 + srow) * KD;
  }
  const size_t br0 = (size_t)(colTile + srow) * KD;
  const size_t br1 = (size_t)(colTile + 64 + srow) * KD;

  f32x4 acc[4][4];
#pragma unroll
  for (int i = 0; i < 4; ++i)
#pragma unroll
    for (int j = 0; j < 4; ++j) acc[i][j] = (f32x4){0.f, 0.f, 0.f, 0.f};

  const int fr = l & 15;
  const int q = l >> 4;
  const int foff = (q ^ ((fr >> 1) & 3)) << 3;  // swizzled frag read offset

  // prologue: load chunk 0 into regs
  int4 vAh0 = *(const int4*)(Ah + ar0 + skE);
  int4 vAh1 = *(const int4*)(Ah + ar1 + skE);
  int4 vAl0 = *(const int4*)(Al + ar0 + skE);
  int4 vAl1 = *(const int4*)(Al + ar1 + skE);
  int4 vBh0 = *(const int4*)(Bh + br0 + skE);
  int4 vBh1 = *(const int4*)(Bh + br1 + skE);
  int4 vBl0 = *(const int4*)(Bl + br0 + skE);
  int4 vBl1 = *(const int4*)(Bl + br1 + skE);

  for (int kk = 0; kk < KD; kk += BK) {
    __syncthreads();  // all waves done reading previous chunk's frags
    *(int4*)(sAh + wOff0) = vAh0; *(int4*)(sAh + wOff1) = vAh1;
    *(int4*)(sAl + wOff0) = vAl0; *(int4*)(sAl + wOff1) = vAl1;
    *(int4*)(sBh + wOff0) = vBh0; *(int4*)(sBh + wOff1) = vBh1;
    *(int4*)(sBl + wOff0) = vBl0; *(int4*)(sBl + wOff1) = vBl1;
    __syncthreads();  // staging visible
    if (kk + BK < KD) {  // prefetch next chunk; latency hidden by frag+MFMA phase
      const int nk = kk + BK + skE;
      vAh0 = *(const int4*)(Ah + ar0 + nk);
      vAh1 = *(const int4*)(Ah + ar1 + nk);
      vAl0 = *(const int4*)(Al + ar0 + nk);
      vAl1 = *(const int4*)(Al + ar1 + nk);
      vBh0 = *(const int4*)(Bh + br0 + nk);
      vBh1 = *(const int4*)(Bh + br1 + nk);
      vBl0 = *(const int4*)(Bl + br0 + nk);
      vBl1 = *(const int4*)(Bl + br1 + nk);
    }

    bf16x8 afh[4], afl[4], bfh[4], bfl[4];
#pragma unroll
    for (int mt = 0; mt < 4; ++mt) {
      const int o = ((wr + (mt << 4) + fr) << 5) + foff;
      afh[mt] = *(const bf16x8*)(sAh + o);
      afl[mt] = *(const bf16x8*)(sAl + o);
    }
#pragma unroll
    for (int nt = 0; nt < 4; ++nt) {
      const int o = ((wc + (nt << 4) + fr) << 5) + foff;
      bfh[nt] = *(const bf16x8*)(sBh + o);
      bfl[nt] = *(const bf16x8*)(sBl + o);
    }
#pragma unroll
    for (int mt = 0; mt < 4; ++mt)
#pragma unroll
      for (int nt = 0; nt < 4; ++nt) {
        acc[mt][nt] = __builtin_amdgcn_mfma_f32_16x16x32_bf16(afh[mt], bfh[nt], acc[mt][nt], 0, 0, 0);
        acc[mt][nt] = __builtin_amdgcn_mfma_f32_16x16x32_bf16(afh[mt], bfl[nt], acc[mt][nt], 0, 0, 0);
        acc[mt][nt] = __builtin_amdgcn_mfma_f32_16x16x32_bf16(afl[mt], bfh[nt], acc[mt][nt], 0, 0, 0);
      }
  }

  const int quad = l >> 4;
  if (eMode == 0) {
    // C/D layout: col = lane&15, row = quad*4 + reg
#pragma unroll
    for (int mt = 0; mt < 4; ++mt) {
#pragma unroll
      for (int reg = 0; reg < 4; ++reg) {
        const int row = rowTile + wr + (mt << 4) + (quad << 2) + reg;
        const float xn = rowNorm[row];
        unsigned long long key = ~0ULL;
#pragma unroll
        for (int nt = 0; nt < 4; ++nt) {
          const int col = colTile + wc + (nt << 4) + fr;
          float d = (xn + colNorm[col]) - 2.0f * acc[mt][nt][reg];
          unsigned ub = __float_as_uint(d);
          ub = (ub & 0x80000000u) ? ~ub : (ub | 0x80000000u);
          unsigned long long k2 = ((unsigned long long)ub << 32) | (unsigned long long)(unsigned)col;
          if (k2 < key) key = k2;
        }
#pragma unroll
        for (int off = 1; off < 16; off <<= 1) {
          unsigned long long o = __shfl_xor(key, off, 64);
          if (o < key) key = o;
        }
        if (fr == 0) atomicMin(amin + row, key);
      }
    }
  } else {
#pragma unroll
    for (int mt = 0; mt < 4; ++mt) {
#pragma unroll
      for (int reg = 0; reg < 4; ++reg) {
        const int row = rowTile + wr + (mt << 4) + (quad << 2) + reg;
#pragma unroll
        for (int nt = 0; nt < 4; ++nt) {
          const int col = colTile + wc + (nt << 4) + fr;
          C[(size_t)row * KD + col] = acc[mt][nt][reg] + bias[col];
        }
      }
    }
  }
}

// ---- LN + leaky -> influence(bf16); residual hi/lo + norms ----
__global__ __launch_bounds__(256) void ln_residual(
    const float* __restrict__ h, const float* __restrict__ g, const float* __restrict__ be,
    const float* __restrict__ z, const float* __restrict__ gRaw,
    __hip_bfloat16* __restrict__ infl, float* __restrict__ rn,
    __hip_bfloat16* __restrict__ rH, __hip_bfloat16* __restrict__ rL) {
  __shared__ float sred[4];
  const int row = blockIdx.x, t = threadIdx.x;
  const size_t base = (size_t)row * KD;
  float h0 = h[base + t], h1 = h[base + t + 256];
  float m = block_sum(h0 + h1, sred) * (1.0f / 512.0f);
  float d0 = h0 - m, d1 = h1 - m;
  float var = block_sum(d0 * d0 + d1 * d1, sred) * (1.0f / 512.0f);
  float sq = sqrtf(var + 1e-5f);
  float gc = sigmoidf_(gRaw[0]);
  float v0 = d0 / sq * g[t] + be[t];
  float v1 = d1 / sq * g[t + 256] + be[t + 256];
  v0 = v0 > 0.0f ? v0 : 0.1f * v0;
  v1 = v1 > 0.0f ? v1 : 0.1f * v1;
  infl[base + t] = __float2bfloat16(v0);
  infl[base + t + 256] = __float2bfloat16(v1);
  float zf0 = z[(size_t)row * 1024 + 512 + t];
  float zf1 = z[(size_t)row * 1024 + 512 + t + 256];
  float r0 = zf0 - gc * v0, r1 = zf1 - gc * v1;
  __hip_bfloat16 hh, ll;
  split_bf16(r0, &hh, &ll);
  rH[base + t] = hh; rL[base + t] = ll;
  split_bf16(r1, &hh, &ll);
  rH[base + t + 256] = hh; rL[base + t + 256] = ll;
  float rs = block_sum(r0 * r0 + r1 * r1, sred);
  if (t == 0) rn[row] = rs;
}

// ---- LN+leaky on h2, gather q_c/q_f, outputs + loss partials ----
__global__ __launch_bounds__(256) void finalize(
    const float* __restrict__ h, const float* __restrict__ g, const float* __restrict__ be,
    const __hip_bfloat16* __restrict__ infl,
    const unsigned long long* __restrict__ amc, const unsigned long long* __restrict__ amf,
    const float* __restrict__ z, const float* __restrict__ ce, const float* __restrict__ fe,
    const float* __restrict__ gcRaw, const float* __restrict__ gfRaw,
    float* __restrict__ out, float* __restrict__ lossp) {
  __shared__ float sred[4];
  const int row = blockIdx.x, t = threadIdx.x;
  const size_t base = (size_t)row * KD;
  float h0 = h[base + t], h1 = h[base + t + 256];
  float m = block_sum(h0 + h1, sred) * (1.0f / 512.0f);
  float d0 = h0 - m, d1 = h1 - m;
  float var = block_sum(d0 * d0 + d1 * d1, sred) * (1.0f / 512.0f);
  float sq = sqrtf(var + 1e-5f);
  float fb0 = d0 / sq * g[t] + be[t];
  float fb1 = d1 / sq * g[t + 256] + be[t + 256];
  fb0 = fb0 > 0.0f ? fb0 : 0.1f * fb0;
  fb1 = fb1 > 0.0f ? fb1 : 0.1f * fb1;
  float gc = sigmoidf_(gcRaw[0]);
  float gf = sigmoidf_(gfRaw[0]);
  unsigned ic = (unsigned)(amc[row] & 0xffffffffULL);
  unsigned ifx = (unsigned)(amf[row] & 0xffffffffULL);
  float loc = 0.0f;
#pragma unroll
  for (int j = 0; j < 2; ++j) {
    int c = t + j * 256;
    float fb = j ? fb1 : fb0;
    float qc = ce[(size_t)ic * KD + c];
    float qf = fe[(size_t)ifx * KD + c];
    float zc = z[(size_t)row * 1024 + c];
    float zf = z[(size_t)row * 1024 + 512 + c];
    float fl = __bfloat162float(infl[base + c]);
    out[(size_t)row * 1024 + c] = qc + 0.1f * gf * fb;
    out[(size_t)row * 1024 + 512 + c] = qf + gc * fl;
    float dc = qc - zc;
    float res = zf - gc * fl;
    float df = qf - res;
    loc += dc * dc + df * df;
  }
  float ls = block_sum(loc, sred);
  if (t == 0) atomicAdd(lossp, ls);
}

__global__ void loss_write(const float* __restrict__ lossp, float* __restrict__ out) {
  out[0] = 1.25f * lossp[0] / (8192.0f * 512.0f);
}

extern "C" void kernel_launch(void* const* d_in, const int* in_sizes, int n_in,
                              void* d_out, int out_size, void* d_ws, size_t ws_size,
                              hipStream_t stream) {
  const float* z      = (const float*)d_in[0];
  const float* ce     = (const float*)d_in[1];
  const float* fe     = (const float*)d_in[2];
  const float* w_c2f  = (const float*)d_in[3];
  const float* b_c2f  = (const float*)d_in[4];
  const float* g_c2f  = (const float*)d_in[5];
  const float* be_c2f = (const float*)d_in[6];
  const float* w_f2c  = (const float*)d_in[7];
  const float* b_f2c  = (const float*)d_in[8];
  const float* g_f2c  = (const float*)d_in[9];
  const float* be_f2c = (const float*)d_in[10];
  const float* gcRaw  = (const float*)d_in[11];
  const float* gfRaw  = (const float*)d_in[12];
  float* out = (float*)d_out;
  char* ws = (char*)d_ws;

  float* cn = (float*)(ws + OFF_CN);
  float* fn = (float*)(ws + OFF_FN);
  float* zn = (float*)(ws + OFF_ZN);
  float* rn = (float*)(ws + OFF_RN);
  float* lossp = (float*)(ws + OFF_LOSS);
  unsigned long long* amc = (unsigned long long*)(ws + OFF_AMC);
  unsigned long long* amf = (unsigned long long*)(ws + OFF_AMF);
  __hip_bfloat16* ceH = (__hip_bfloat16*)(ws + OFF_CEH);
  __hip_bfloat16* ceL = (__hip_bfloat16*)(ws + OFF_CEL);
  __hip_bfloat16* feH = (__hip_bfloat16*)(ws + OFF_FEH);
  __hip_bfloat16* feL = (__hip_bfloat16*)(ws + OFF_FEL);
  __hip_bfloat16* zcH = (__hip_bfloat16*)(ws + OFF_ZCH);
  __hip_bfloat16* zcL = (__hip_bfloat16*)(ws + OFF_ZCL);
  __hip_bfloat16* rH  = (__hip_bfloat16*)(ws + OFF_RH);
  __hip_bfloat16* rL  = (__hip_bfloat16*)(ws + OFF_RL);
  __hip_bfloat16* w1H = (__hip_bfloat16*)(ws + OFF_W1H);
  __hip_bfloat16* w1L = (__hip_bfloat16*)(ws + OFF_W1L);
  __hip_bfloat16* w2H = (__hip_bfloat16*)(ws + OFF_W2H);
  __hip_bfloat16* w2L = (__hip_bfloat16*)(ws + OFF_W2L);
  float* h = (float*)(ws + OFF_H);
  __hip_bfloat16* infl = (__hip_bfloat16*)(ws + OFF_INFL);

  // init argmin keys (coarse+fine contiguous) to u64 max
  hipMemsetAsync(ws + OFF_AMC, 0xFF, 131072, stream);

  // norms + hi/lo splits; zero loss
  prep<<<21504, 256, 0, stream>>>(ce, fe, z, w_c2f, w_f2c, cn, fn, zn,
                                  ceH, ceL, feH, feL, zcH, zcL,
                                  w1H, w1L, w2H, w2L, lossp);

  // coarse VQ: 8192 x 4096, argmin
  gemm4<<<dim3(32, 64), 256, 0, stream>>>(zcH, zcL, nullptr, ceH, ceL,
                                          zn, cn, amc, nullptr, nullptr, 0);

  // MLP1: h = gather(ce, amc) @ w_c2f^T + b
  gemm4<<<dim3(4, 64), 256, 0, stream>>>(ceH, ceL, amc, w1H, w1L,
                                         nullptr, nullptr, nullptr, b_c2f, h, 1);

  // LN + leaky -> influence (bf16); residual hi/lo + norms
  ln_residual<<<8192, 256, 0, stream>>>(h, g_c2f, be_c2f, z, gcRaw, infl, rn, rH, rL);

  // fine VQ: 8192 x 8192, argmin
  gemm4<<<dim3(64, 64), 256, 0, stream>>>(rH, rL, nullptr, feH, feL,
                                          rn, fn, amf, nullptr, nullptr, 0);

  // MLP2: h = gather(fe, amf) @ w_f2c^T + b
  gemm4<<<dim3(4, 64), 256, 0, stream>>>(feH, feL, amf, w2H, w2L,
                                         nullptr, nullptr, nullptr, b_f2c, h, 1);

  // outputs + loss
  finalize<<<8192, 256, 0, stream>>>(h, g_f2c, be_f2c, infl, amc, amf, z, ce, fe,
                                     gcRaw, gfRaw, out, lossp);
  loss_write<<<1, 1, 0, stream>>>(lossp, out + (size_t)8192 * 1024);
}